// Round 13
// baseline (275.416 us; speedup 1.0000x reference)
//
#include <hip/hip_runtime.h>

typedef __bf16 bf16_t;
typedef bf16_t bf16x8 __attribute__((ext_vector_type(8)));
typedef _Float16 f16_t;
typedef __fp16 hf16x2 __attribute__((ext_vector_type(2)));   // cvt_pkrtz return type
typedef f16_t f16x8 __attribute__((ext_vector_type(8)));
typedef float floatx4 __attribute__((ext_vector_type(4)));
typedef float floatx16 __attribute__((ext_vector_type(16)));

#define S_LEN 2048
#define DIM 768
#define NH 16
#define HD 48
#define HDP 64
#define BHEADS 64          // B * NH
#define ATT_SCALE 0.14433756729740643f  // 1/sqrt(48)
#define W_ELEMS (DIM * DIM)

typedef unsigned short u16;
typedef unsigned int u32;

__device__ __forceinline__ u16 f2b(float f) {
  union { float f; u32 i; } z; z.f = f;
  u32 i = z.i;
  return (u16)((i + 0x7fffu + ((i >> 16) & 1u)) >> 16);  // RNE
}
__device__ __forceinline__ u32 pack2(float a, float b) {
  return (u32)f2b(a) | ((u32)f2b(b) << 16);
}
__device__ __forceinline__ u32 pkrtz2(float a, float b) {   // 2x f32 -> packed f16
  union { hf16x2 h; u32 u; } z;
  z.h = __builtin_amdgcn_cvt_pkrtz(a, b);
  return z.u;
}
// v_permlane32_swap_b32: a' = [a.lanes0-31, b.lanes0-31]; b' = [a.lanes32-63, b.lanes32-63]
__device__ __forceinline__ void pl32swap(u32& a, u32& b) {
  asm("v_permlane32_swap_b32 %0, %1" : "+v"(a), "+v"(b));
}
// async global->LDS DMA, 16B per lane. LDS dest is wave-uniform base + lane*16;
// global src is per-lane. vmcnt-counted; __syncthreads() drains it.
__device__ __forceinline__ void gld_lds16(const void* g, void* l) {
  __builtin_amdgcn_global_load_lds(
      (const __attribute__((address_space(1))) u32*)g,
      (__attribute__((address_space(3))) u32*)l, 16, 0, 0);
}

// ---------------------------------------------------------------------------
// Fused fp32 -> bf16 convert for x (blocks 0..3071) and the 4 weight
// matrices (blocks 3072..4223, 288 per matrix).
// ---------------------------------------------------------------------------
__global__ __launch_bounds__(256) void cvt_all(
    const float* __restrict__ x,
    const float* __restrict__ w0, const float* __restrict__ w1,
    const float* __restrict__ w2, const float* __restrict__ w3,
    u16* __restrict__ x_dst, u16* __restrict__ w_dst)
{
  const int blk = blockIdx.x;
  const float* src;
  u16* dst;
  int idx;
  if (blk < 3072) {
    src = x; dst = x_dst; idx = blk * 256 + threadIdx.x;
  } else {
    int wb = blk - 3072;
    int j = wb / 288;
    src = (j == 0) ? w0 : (j == 1) ? w1 : (j == 2) ? w2 : w3;
    dst = w_dst + (size_t)j * W_ELEMS;
    idx = (wb - j * 288) * 256 + threadIdx.x;
  }
  const float4* s = (const float4*)src;
  float4 a = s[idx * 2], b = s[idx * 2 + 1];
  *(uint4*)&dst[(size_t)idx * 8] =
      make_uint4(pack2(a.x, a.y), pack2(a.z, a.w), pack2(b.x, b.y), pack2(b.z, b.w));
}

// ===========================================================================
// GEMM staging via global_load_lds, DOUBLE-BUFFERED, ONE barrier per K-step
// (round-12 verified). LINEAR LDS; source-side column XOR swizzle
// ccg = ccl ^ ((r>>1)&3), same XOR on read (rule 21) -> conflict-free.
// ROUND 13: Q/K blocks use SWAPPED MFMA operands (mfma(W-frag, x-frag) =
// W.x^T): D's reg-index dim becomes the W-col (d), lane dim the x-row (s),
// so each lane holds 4 consecutive d for one s -> one aligned 8B uint2 store
// per fragment (16 stores/thread vs 64 scalar u16), float4 bias loads, 4x
// fewer col/48 divisions. 4-runs never cross a head boundary (48%4==0).
// V blocks keep the unswapped path (LDS-transpose epilogue needs it).
// Numerics bit-identical: same K-order, same bias-add order, same rounding.
// ===========================================================================

// ---------------------------------------------------------------------------
// Fused QKV GEMM, 128x128 tile. grid 1152 = 64 m x 18 n; mat = bn/6
// (0=Q,1=K,2=V). Q/K: bf16 head-scatter [bh][s][64] (Q scaled), swapped
// operands; V: f16 V^T [bh][d][s] via two-pass 64-col LDS transpose.
// LDS: 2 x (As 128x32 + Bs 128x32) = 16384 u16 = 32 KB; T overlay 8704 u16.
// ---------------------------------------------------------------------------
__global__ __launch_bounds__(256) void gemm_qkv(
    const u16* __restrict__ A, const u16* __restrict__ Wbase,
    const float* __restrict__ bq, const float* __restrict__ bk,
    const float* __restrict__ bv,
    u16* __restrict__ q_out, u16* __restrict__ k_out, u16* __restrict__ v_out)
{
  __shared__ __attribute__((aligned(16))) u16 smem[16384];

  const int tid = threadIdx.x;
  const int w = tid >> 6, lane = tid & 63, lo = lane & 15, quad = lane >> 4;
  const int wr = w >> 1, wc = w & 1;
  const int bm = blockIdx.x & 63, bn = blockIdx.x >> 6;
  const int mat = bn / 6;                  // 0=Q, 1=K, 2=V
  const int n0 = (bn - mat * 6) * 128;
  const int m0 = bm * 128;
  const u16* W = Wbase + (size_t)mat * W_ELEMS;
  const float* bias = mat == 0 ? bq : (mat == 1 ? bk : bv);
  const float scale = mat == 0 ? ATT_SCALE : 1.0f;

  size_t aoff[2], boff[2];
#pragma unroll
  for (int it = 0; it < 2; ++it) {
    int c = tid + it * 256, r = c >> 2, ccl = c & 3;
    int ccg = ccl ^ ((r >> 1) & 3);
    aoff[it] = (size_t)(m0 + r) * DIM + ccg * 8;
    boff[it] = (size_t)(n0 + r) * DIM + ccg * 8;
  }

  floatx4 acc[4][4];
#pragma unroll
  for (int mi = 0; mi < 4; mi++)
#pragma unroll
    for (int ni = 0; ni < 4; ni++) acc[mi][ni] = (floatx4){0.f, 0.f, 0.f, 0.f};

  // prologue: issue K-step 0 into buffer 0 (As at 0, Bs at 4096)
#pragma unroll
  for (int it = 0; it < 2; ++it) {
    gld_lds16(&A[aoff[it]], &smem[(it * 256 + w * 64) * 8]);
    gld_lds16(&W[boff[it]], &smem[4096 + (it * 256 + w * 64) * 8]);
  }

  for (int ks = 0; ks < 24; ++ks) {
    const int cur = ks & 1;
    u16* Asc = smem + cur * 8192;
    u16* Bsc = Asc + 4096;
    __syncthreads();     // vmcnt(0) drain: buf cur ready; buf cur^1 readers done
    if (ks < 23) {
      const int kn = (ks + 1) * 32;
      u16* Asn = smem + (cur ^ 1) * 8192;
      u16* Bsn = Asn + 4096;
#pragma unroll
      for (int it = 0; it < 2; ++it) {
        gld_lds16(&A[aoff[it] + kn], &Asn[(it * 256 + w * 64) * 8]);
        gld_lds16(&W[boff[it] + kn], &Bsn[(it * 256 + w * 64) * 8]);
      }
    }

    bf16x8 af[4], bfr[4];
#pragma unroll
    for (int mi = 0; mi < 4; mi++) {
      int row = wr * 64 + mi * 16 + lo;
      int s = quad ^ ((row >> 1) & 3);
      af[mi] = *(const bf16x8*)&Asc[row * 32 + s * 8];
    }
#pragma unroll
    for (int ni = 0; ni < 4; ni++) {
      int row = wc * 64 + ni * 16 + lo;
      int s = quad ^ ((row >> 1) & 3);
      bfr[ni] = *(const bf16x8*)&Bsc[row * 32 + s * 8];
    }
    if (mat < 2) {
      // swapped: acc[mi][ni] = W-frag(ni) . x-frag(mi)^T
#pragma unroll
      for (int mi = 0; mi < 4; mi++)
#pragma unroll
        for (int ni = 0; ni < 4; ni++)
          acc[mi][ni] = __builtin_amdgcn_mfma_f32_16x16x32_bf16(bfr[ni], af[mi], acc[mi][ni], 0, 0, 0);
    } else {
#pragma unroll
      for (int mi = 0; mi < 4; mi++)
#pragma unroll
        for (int ni = 0; ni < 4; ni++)
          acc[mi][ni] = __builtin_amdgcn_mfma_f32_16x16x32_bf16(af[mi], bfr[ni], acc[mi][ni], 0, 0, 0);
    }
  }

  if (mat == 2) {
    u16 (*T)[136] = (u16(*)[136])smem;
    const int b = m0 >> 11, s0 = m0 & 2047;
#pragma unroll
    for (int half = 0; half < 2; ++half) {
      __syncthreads();   // pass 0: last ds_reads done; pass 1: prev copy done
      if (wc == half) {
#pragma unroll
        for (int mi = 0; mi < 4; mi++)
#pragma unroll
          for (int ni = 0; ni < 4; ni++) {
            int colL = ni * 16 + lo;
            float bb = bias[n0 + half * 64 + colL];
            float v0 = acc[mi][ni][0] + bb, v1 = acc[mi][ni][1] + bb;
            float v2 = acc[mi][ni][2] + bb, v3 = acc[mi][ni][3] + bb;
            *(uint2*)&T[colL][wr * 64 + mi * 16 + quad * 4] =
                make_uint2(pkrtz2(v0, v1), pkrtz2(v2, v3));
          }
      }
      __syncthreads();
#pragma unroll
      for (int it = 0; it < 4; ++it) {
        int ch = tid + it * 256;
        int col = ch >> 4, sc = ch & 15;
        int gcol = n0 + half * 64 + col;
        int h = gcol / HD, d = gcol - h * HD;
        size_t dst = ((size_t)(b * NH + h) * HDP + d) * S_LEN + s0 + sc * 8;
        *(uint4*)&v_out[dst] = *(const uint4*)&T[col][sc * 8];
      }
    }
    return;
  }

  // Q/K epilogue (swapped layout): lane holds 4 consecutive d for one s.
  u16* out = mat == 0 ? q_out : k_out;
#pragma unroll
  for (int mi = 0; mi < 4; mi++) {
    int srow = m0 + wr * 64 + mi * 16 + lo;
    int b = srow >> 11, s = srow & 2047;
#pragma unroll
    for (int ni = 0; ni < 4; ni++) {
      int colb = n0 + wc * 64 + ni * 16 + quad * 4;   // 4-run, within one head
      float4 bb = *(const float4*)&bias[colb];
      float v0 = (acc[mi][ni][0] + bb.x) * scale;
      float v1 = (acc[mi][ni][1] + bb.y) * scale;
      float v2 = (acc[mi][ni][2] + bb.z) * scale;
      float v3 = (acc[mi][ni][3] + bb.w) * scale;
      int h = colb / HD, d = colb - h * HD;
      *(uint2*)&out[((size_t)((b * NH + h) * S_LEN + s)) * HDP + d] =
          make_uint2(pack2(v0, v1), pack2(v2, v3));
    }
  }
}

// ---------------------------------------------------------------------------
// Wo GEMM: A = attn out HEAD-MAJOR [bh][s][48] bf16; out fp32 [8192][768].
// Tile 128x64, grid 768, double-buffered gld_lds staging (one barrier/K-step).
// LDS: 2 x (As 4096 + Bs 2048) = 12288 u16 = 24 KB. (round-12 verified)
// ---------------------------------------------------------------------------
__global__ __launch_bounds__(256) void gemm_wo(
    const u16* __restrict__ A, const u16* __restrict__ W,
    const float* __restrict__ bias, float* __restrict__ out)
{
  __shared__ __attribute__((aligned(16))) u16 smem[12288];

  const int tid = threadIdx.x;
  const int w = tid >> 6, lane = tid & 63, lo = lane & 15, quad = lane >> 4;
  const int bm = blockIdx.x & 63, bn = blockIdx.x >> 6;
  const int m0 = bm * 128, n0 = bn * 64;

  int ar[2], accg[2];
#pragma unroll
  for (int it = 0; it < 2; ++it) {
    int c = tid + it * 256, r = c >> 2, ccl = c & 3;
    ar[it] = m0 + r;
    accg[it] = (ccl ^ ((r >> 1) & 3)) * 8;
  }
  size_t boff;
  {
    int r = tid >> 2, ccl = tid & 3;
    boff = (size_t)(n0 + r) * DIM + (ccl ^ ((r >> 1) & 3)) * 8;
  }

  floatx4 acc[2][4];
#pragma unroll
  for (int mi = 0; mi < 2; mi++)
#pragma unroll
    for (int ni = 0; ni < 4; ni++) acc[mi][ni] = (floatx4){0.f, 0.f, 0.f, 0.f};

  // prologue: K-step 0 into buffer 0
#pragma unroll
  for (int it = 0; it < 2; ++it) {
    int row = ar[it], c8 = accg[it];
    int h = c8 / HD, d = c8 - h * HD;
    int b = row >> 11, s = row & 2047;
    gld_lds16(&A[((size_t)((b * NH + h) * S_LEN + s)) * HD + d],
              &smem[(it * 256 + w * 64) * 8]);
  }
  gld_lds16(&W[boff], &smem[4096 + (w * 64) * 8]);

  for (int ks = 0; ks < 24; ++ks) {
    const int cur = ks & 1;
    u16* Asc = smem + cur * 6144;
    u16* Bsc = Asc + 4096;
    __syncthreads();
    if (ks < 23) {
      const int kn = (ks + 1) * 32;
      u16* Asn = smem + (cur ^ 1) * 6144;
      u16* Bsn = Asn + 4096;
#pragma unroll
      for (int it = 0; it < 2; ++it) {
        int row = ar[it], c8 = kn + accg[it];
        int h = c8 / HD, d = c8 - h * HD;
        int b = row >> 11, s = row & 2047;
        gld_lds16(&A[((size_t)((b * NH + h) * S_LEN + s)) * HD + d],
                  &Asn[(it * 256 + w * 64) * 8]);
      }
      gld_lds16(&W[boff + kn], &Bsn[(w * 64) * 8]);
    }

    bf16x8 af[2], bfr[4];
#pragma unroll
    for (int mi = 0; mi < 2; mi++) {
      int row = w * 32 + mi * 16 + lo;
      int s = quad ^ ((row >> 1) & 3);
      af[mi] = *(const bf16x8*)&Asc[row * 32 + s * 8];
    }
#pragma unroll
    for (int ni = 0; ni < 4; ni++) {
      int row = ni * 16 + lo;
      int s = quad ^ ((row >> 1) & 3);
      bfr[ni] = *(const bf16x8*)&Bsc[row * 32 + s * 8];
    }
#pragma unroll
    for (int mi = 0; mi < 2; mi++)
#pragma unroll
      for (int ni = 0; ni < 4; ni++)
        acc[mi][ni] = __builtin_amdgcn_mfma_f32_16x16x32_bf16(af[mi], bfr[ni], acc[mi][ni], 0, 0, 0);
  }

#pragma unroll
  for (int mi = 0; mi < 2; mi++)
#pragma unroll
    for (int ni = 0; ni < 4; ni++)
#pragma unroll
      for (int r = 0; r < 4; r++) {
        int row = m0 + w * 32 + mi * 16 + quad * 4 + r;
        int col = n0 + ni * 16 + lo;
        out[(size_t)row * DIM + col] = acc[mi][ni][r] + bias[col];
      }
}

// ---------------------------------------------------------------------------
// Flash attention (round-9 verified, 105-111 us): 32x32x16 MFMA, swapped
// QK^T, P in registers via cvt_pkrtz + permlane32_swap, f32 denominator,
// XCD swizzle, head-major O. UNCHANGED.
// ---------------------------------------------------------------------------
#define STG_LOAD(k0n) do {                                                     \
  _Pragma("unroll")                                                            \
  for (int it = 0; it < 3; ++it) {                                             \
    int c = tid + it * 256;                                                    \
    if (c < 384) {                                                             \
      int r = c / 6, cc = c - r * 6;                                           \
      stg[it] = *(const uint4*)&K[base + (size_t)((k0n) + r) * HDP + cc * 8];  \
    } else {                                                                   \
      int c2 = c - 384, r = c2 >> 3, cc = c2 & 7;                              \
      stg[it] = *(const uint4*)&V[base + (size_t)r * S_LEN + (k0n) + cc * 8];  \
    }                                                                          \
  }                                                                            \
} while (0)

#define STG_WRITE(bufi) do {                                                   \
  _Pragma("unroll")                                                            \
  for (int it = 0; it < 3; ++it) {                                             \
    int c = tid + it * 256;                                                    \
    if (c < 384) {                                                             \
      int r = c / 6, cc = c - r * 6;                                           \
      *(uint4*)&Ks[bufi][r][cc * 8] = stg[it];                                 \
    } else {                                                                   \
      int c2 = c - 384, r = c2 >> 3, cc = c2 & 7;                              \
      *(uint4*)&Vt[bufi][r][cc * 8] = stg[it];                                 \
    }                                                                          \
  }                                                                            \
} while (0)

__global__ __launch_bounds__(256, 2) void attn_kernel(
    const u16* __restrict__ Q, const u16* __restrict__ K,
    const u16* __restrict__ V, u16* __restrict__ O)
{
  __shared__ __attribute__((aligned(16))) u16 Ks[2][64][56];  // keys x d(<48)
  __shared__ __attribute__((aligned(16))) u16 Vt[2][64][72];  // d x keys (f16)

  const int tid = threadIdx.x;
  const int w = tid >> 6, lane = tid & 63, l31 = lane & 31, hi = lane >> 5;
  const int flat = blockIdx.x;
  const int xcd = flat & 7, sub = flat >> 3;          // sub in [0,64)
  const int bh = xcd * 8 + (sub >> 3);                // 8 bh per XCD
  const int q0 = (sub & 7) * 256;                     // 8 q-blocks per bh
  const size_t base = (size_t)bh * S_LEN * HDP;

  bf16x8 qf[2][3];
#pragma unroll
  for (int t = 0; t < 2; t++)
#pragma unroll
    for (int ks = 0; ks < 3; ks++)
      qf[t][ks] = *(const bf16x8*)
          &Q[base + (size_t)(q0 + w * 64 + t * 32 + l31) * HDP + ks * 16 + hi * 8];

  floatx16 oacc[2][2];
#pragma unroll
  for (int t = 0; t < 2; t++)
#pragma unroll
    for (int nd = 0; nd < 2; nd++)
#pragma unroll
      for (int r = 0; r < 16; r++) oacc[t][nd][r] = 0.f;

  float l_lane[2] = {0.f, 0.f};

  uint4 stg[3];
  STG_LOAD(0);
  STG_WRITE(0);

  for (int ti = 0; ti < 32; ++ti) {
    const int cur = ti & 1;
    if (ti < 31) STG_LOAD((ti + 1) * 64);   // in flight across the barrier
    __syncthreads();

    bf16x8 ak[2][3];
#pragma unroll
    for (int na = 0; na < 2; na++)
#pragma unroll
      for (int ks = 0; ks < 3; ks++)
        ak[na][ks] = *(const bf16x8*)&Ks[cur][na * 32 + l31][ks * 16 + hi * 8];

    u32 pk[2][2][8];
#pragma unroll
    for (int t = 0; t < 2; t++) {
      floatx16 s0, s1;
#pragma unroll
      for (int r = 0; r < 16; r++) { s0[r] = 0.f; s1[r] = 0.f; }
#pragma unroll
      for (int ks = 0; ks < 3; ks++) {
        s0 = __builtin_amdgcn_mfma_f32_32x32x16_bf16(ak[0][ks], qf[t][ks], s0, 0, 0, 0);
        s1 = __builtin_amdgcn_mfma_f32_32x32x16_bf16(ak[1][ks], qf[t][ks], s1, 0, 0, 0);
      }
#pragma unroll
      for (int m = 0; m < 8; m++) {
        float a0 = __expf(s0[2 * m]), a1 = __expf(s0[2 * m + 1]);
        float b0 = __expf(s1[2 * m]), b1 = __expf(s1[2 * m + 1]);
        l_lane[t] += (a0 + a1) + (b0 + b1);
        pk[t][0][m] = pkrtz2(a0, a1);
        pk[t][1][m] = pkrtz2(b0, b1);
      }
    }

#pragma unroll
    for (int kt = 0; kt < 4; kt++) {
      f16x8 bv0 = *(const f16x8*)&Vt[cur][l31][kt * 16 + hi * 8];
      f16x8 bv1 = *(const f16x8*)&Vt[cur][32 + l31][kt * 16 + hi * 8];
      const int na = kt >> 1, k4 = (kt & 1) * 4;
#pragma unroll
      for (int t = 0; t < 2; t++) {
        u32 w0 = pk[t][na][k4 + 0], w2 = pk[t][na][k4 + 2];
        u32 w1 = pk[t][na][k4 + 1], w3 = pk[t][na][k4 + 3];
        pl32swap(w0, w2);
        pl32swap(w1, w3);
        union { u32 u[4]; f16x8 f; } af;
        af.u[0] = w0; af.u[1] = w1; af.u[2] = w2; af.u[3] = w3;
        oacc[t][0] = __builtin_amdgcn_mfma_f32_32x32x16_f16(af.f, bv0, oacc[t][0], 0, 0, 0);
        oacc[t][1] = __builtin_amdgcn_mfma_f32_32x32x16_f16(af.f, bv1, oacc[t][1], 0, 0, 0);
      }
    }

    if (ti < 31) STG_WRITE(cur ^ 1);
  }

  const size_t obase = (size_t)bh * S_LEN * HD;
  float lt_full[2];
#pragma unroll
  for (int t = 0; t < 2; t++)
    lt_full[t] = l_lane[t] + __shfl_xor(l_lane[t], 32);
#pragma unroll
  for (int t = 0; t < 2; t++) {
#pragma unroll
    for (int r = 0; r < 16; r++) {
      int q_local = (r & 3) + 8 * (r >> 2) + 4 * hi;
      float l_r = __shfl(lt_full[t], q_local);
      float inv = 1.f / l_r;
      int q = q0 + w * 64 + t * 32 + q_local;
      u16* orow = O + obase + (size_t)q * HD;
      orow[l31] = f2b(oacc[t][0][r] * inv);
      if (l31 < 16) orow[32 + l31] = f2b(oacc[t][1][r] * inv);
    }
  }
}

// ---------------------------------------------------------------------------
extern "C" void kernel_launch(void* const* d_in, const int* in_sizes, int n_in,
                              void* d_out, int out_size, void* d_ws, size_t ws_size,
                              hipStream_t stream)
{
  const float* x  = (const float*)d_in[0];
  const float* Wq = (const float*)d_in[1];
  const float* bq = (const float*)d_in[2];
  const float* Wk = (const float*)d_in[3];
  const float* bk = (const float*)d_in[4];
  const float* Wv = (const float*)d_in[5];
  const float* bv = (const float*)d_in[6];
  const float* Wo = (const float*)d_in[7];
  const float* bo = (const float*)d_in[8];

  u16* ws   = (u16*)d_ws;
  const size_t qkv_elems = (size_t)BHEADS * S_LEN * HDP;  // 8.39M u16 each
  u16* q_ws = ws;                                         // [bh][s][64] bf16
  u16* k_ws = q_ws + qkv_elems;                           // [bh][s][64] bf16
  u16* v_ws = k_ws + qkv_elems;                           // [bh][d][s]  f16 (V^T)
  u16* x_bf = v_ws + qkv_elems;                           // [8192][768] bf16
  u16* a_ws = x_bf;   // aliased: attn writes [bh][s][48] (6.29M u16 = x_bf size)
  u16* w_bf = x_bf + (size_t)8192 * DIM;                  // 4x[768][768] bf16
  u16* wo_bf = w_bf + (size_t)3 * W_ELEMS;

  cvt_all<<<dim3(4224), dim3(256), 0, stream>>>(x, Wq, Wk, Wv, Wo, x_bf, w_bf);
  gemm_qkv<<<dim3(1152), dim3(256), 0, stream>>>(x_bf, w_bf, bq, bk, bv,
                                                 q_ws, k_ws, v_ws);
  attn_kernel<<<dim3(512), dim3(256), 0, stream>>>(q_ws, k_ws, v_ws, a_ws);
  gemm_wo<<<dim3(768), dim3(256), 0, stream>>>(a_ws, wo_bf, bo, (float*)d_out);
}

// Round 14
// 246.945 us; speedup vs baseline: 1.1153x; 1.1153x over previous
//
#include <hip/hip_runtime.h>

typedef __bf16 bf16_t;
typedef bf16_t bf16x8 __attribute__((ext_vector_type(8)));
typedef _Float16 f16_t;
typedef __fp16 hf16x2 __attribute__((ext_vector_type(2)));   // cvt_pkrtz return type
typedef f16_t f16x8 __attribute__((ext_vector_type(8)));
typedef float floatx4 __attribute__((ext_vector_type(4)));
typedef float floatx16 __attribute__((ext_vector_type(16)));

#define S_LEN 2048
#define DIM 768
#define NH 16
#define HD 48
#define HDP 64
#define BHEADS 64          // B * NH
#define ATT_SCALE 0.14433756729740643f  // 1/sqrt(48)
// exp2-fold: Q pre-scaled by lambda*log2(e) in f32 before ONE bf16 rounding
// (same rounding count as lambda alone); attn uses v_exp_f32 directly.
#define QK_SCALE (0.14433756729740643f * 1.44269504088896341f)
#define W_ELEMS (DIM * DIM)

typedef unsigned short u16;
typedef unsigned int u32;

__device__ __forceinline__ u16 f2b(float f) {
  union { float f; u32 i; } z; z.f = f;
  u32 i = z.i;
  return (u16)((i + 0x7fffu + ((i >> 16) & 1u)) >> 16);  // RNE
}
__device__ __forceinline__ u32 pack2(float a, float b) {
  return (u32)f2b(a) | ((u32)f2b(b) << 16);
}
__device__ __forceinline__ u32 pkrtz2(float a, float b) {   // 2x f32 -> packed f16
  union { hf16x2 h; u32 u; } z;
  z.h = __builtin_amdgcn_cvt_pkrtz(a, b);
  return z.u;
}
// v_permlane32_swap_b32: a' = [a.lanes0-31, b.lanes0-31]; b' = [a.lanes32-63, b.lanes32-63]
__device__ __forceinline__ void pl32swap(u32& a, u32& b) {
  asm("v_permlane32_swap_b32 %0, %1" : "+v"(a), "+v"(b));
}
// async global->LDS DMA, 16B per lane. LDS dest is wave-uniform base + lane*16;
// global src is per-lane. vmcnt-counted; __syncthreads() drains it.
__device__ __forceinline__ void gld_lds16(const void* g, void* l) {
  __builtin_amdgcn_global_load_lds(
      (const __attribute__((address_space(1))) u32*)g,
      (__attribute__((address_space(3))) u32*)l, 16, 0, 0);
}

// ---------------------------------------------------------------------------
// Fused fp32 -> bf16 convert for x (blocks 0..3071) and the 4 weight
// matrices (blocks 3072..4223, 288 per matrix).
// ---------------------------------------------------------------------------
__global__ __launch_bounds__(256) void cvt_all(
    const float* __restrict__ x,
    const float* __restrict__ w0, const float* __restrict__ w1,
    const float* __restrict__ w2, const float* __restrict__ w3,
    u16* __restrict__ x_dst, u16* __restrict__ w_dst)
{
  const int blk = blockIdx.x;
  const float* src;
  u16* dst;
  int idx;
  if (blk < 3072) {
    src = x; dst = x_dst; idx = blk * 256 + threadIdx.x;
  } else {
    int wb = blk - 3072;
    int j = wb / 288;
    src = (j == 0) ? w0 : (j == 1) ? w1 : (j == 2) ? w2 : w3;
    dst = w_dst + (size_t)j * W_ELEMS;
    idx = (wb - j * 288) * 256 + threadIdx.x;
  }
  const float4* s = (const float4*)src;
  float4 a = s[idx * 2], b = s[idx * 2 + 1];
  *(uint4*)&dst[(size_t)idx * 8] =
      make_uint4(pack2(a.x, a.y), pack2(a.z, a.w), pack2(b.x, b.y), pack2(b.z, b.w));
}

// ===========================================================================
// GEMM staging via global_load_lds, DOUBLE-BUFFERED, ONE barrier per K-step
// (round-12 verified, 251.3 us). LINEAR LDS; source-side column XOR swizzle
// ccg = ccl ^ ((r>>1)&3), same XOR on read (rule 21) -> conflict-free.
// ROUND 14: operand-swap epilogue REVERTED (round-13 measured -24 us: the
// uint2-per-lane stores land at 128B row stride -> 64 discontiguous 8B
// segments per instruction vs unswapped's 32B-contiguous 16-lane runs).
// ===========================================================================

// ---------------------------------------------------------------------------
// Fused QKV GEMM, 128x128 tile. grid 1152 = 64 m x 18 n; mat = bn/6
// (0=Q,1=K,2=V). Q/K: bf16 head-scatter [bh][s][64] (Q scaled by QK_SCALE);
// V: f16 V^T [bh][d][s] via two-pass 64-col LDS transpose.
// LDS: 2 x (As 128x32 + Bs 128x32) = 16384 u16 = 32 KB; T overlay 8704 u16.
// ---------------------------------------------------------------------------
__global__ __launch_bounds__(256) void gemm_qkv(
    const u16* __restrict__ A, const u16* __restrict__ Wbase,
    const float* __restrict__ bq, const float* __restrict__ bk,
    const float* __restrict__ bv,
    u16* __restrict__ q_out, u16* __restrict__ k_out, u16* __restrict__ v_out)
{
  __shared__ __attribute__((aligned(16))) u16 smem[16384];

  const int tid = threadIdx.x;
  const int w = tid >> 6, lane = tid & 63, lo = lane & 15, quad = lane >> 4;
  const int wr = w >> 1, wc = w & 1;
  const int bm = blockIdx.x & 63, bn = blockIdx.x >> 6;
  const int mat = bn / 6;                  // 0=Q, 1=K, 2=V
  const int n0 = (bn - mat * 6) * 128;
  const int m0 = bm * 128;
  const u16* W = Wbase + (size_t)mat * W_ELEMS;
  const float* bias = mat == 0 ? bq : (mat == 1 ? bk : bv);
  const float scale = mat == 0 ? QK_SCALE : 1.0f;

  size_t aoff[2], boff[2];
#pragma unroll
  for (int it = 0; it < 2; ++it) {
    int c = tid + it * 256, r = c >> 2, ccl = c & 3;
    int ccg = ccl ^ ((r >> 1) & 3);
    aoff[it] = (size_t)(m0 + r) * DIM + ccg * 8;
    boff[it] = (size_t)(n0 + r) * DIM + ccg * 8;
  }

  floatx4 acc[4][4];
#pragma unroll
  for (int mi = 0; mi < 4; mi++)
#pragma unroll
    for (int ni = 0; ni < 4; ni++) acc[mi][ni] = (floatx4){0.f, 0.f, 0.f, 0.f};

  // prologue: issue K-step 0 into buffer 0 (As at 0, Bs at 4096)
#pragma unroll
  for (int it = 0; it < 2; ++it) {
    gld_lds16(&A[aoff[it]], &smem[(it * 256 + w * 64) * 8]);
    gld_lds16(&W[boff[it]], &smem[4096 + (it * 256 + w * 64) * 8]);
  }

  for (int ks = 0; ks < 24; ++ks) {
    const int cur = ks & 1;
    u16* Asc = smem + cur * 8192;
    u16* Bsc = Asc + 4096;
    __syncthreads();     // vmcnt(0) drain: buf cur ready; buf cur^1 readers done
    if (ks < 23) {
      const int kn = (ks + 1) * 32;
      u16* Asn = smem + (cur ^ 1) * 8192;
      u16* Bsn = Asn + 4096;
#pragma unroll
      for (int it = 0; it < 2; ++it) {
        gld_lds16(&A[aoff[it] + kn], &Asn[(it * 256 + w * 64) * 8]);
        gld_lds16(&W[boff[it] + kn], &Bsn[(it * 256 + w * 64) * 8]);
      }
    }

    bf16x8 af[4], bfr[4];
#pragma unroll
    for (int mi = 0; mi < 4; mi++) {
      int row = wr * 64 + mi * 16 + lo;
      int s = quad ^ ((row >> 1) & 3);
      af[mi] = *(const bf16x8*)&Asc[row * 32 + s * 8];
    }
#pragma unroll
    for (int ni = 0; ni < 4; ni++) {
      int row = wc * 64 + ni * 16 + lo;
      int s = quad ^ ((row >> 1) & 3);
      bfr[ni] = *(const bf16x8*)&Bsc[row * 32 + s * 8];
    }
#pragma unroll
    for (int mi = 0; mi < 4; mi++)
#pragma unroll
      for (int ni = 0; ni < 4; ni++)
        acc[mi][ni] = __builtin_amdgcn_mfma_f32_16x16x32_bf16(af[mi], bfr[ni], acc[mi][ni], 0, 0, 0);
  }

  if (mat == 2) {
    u16 (*T)[136] = (u16(*)[136])smem;
    const int b = m0 >> 11, s0 = m0 & 2047;
#pragma unroll
    for (int half = 0; half < 2; ++half) {
      __syncthreads();   // pass 0: last ds_reads done; pass 1: prev copy done
      if (wc == half) {
#pragma unroll
        for (int mi = 0; mi < 4; mi++)
#pragma unroll
          for (int ni = 0; ni < 4; ni++) {
            int colL = ni * 16 + lo;
            float bb = bias[n0 + half * 64 + colL];
            float v0 = acc[mi][ni][0] + bb, v1 = acc[mi][ni][1] + bb;
            float v2 = acc[mi][ni][2] + bb, v3 = acc[mi][ni][3] + bb;
            *(uint2*)&T[colL][wr * 64 + mi * 16 + quad * 4] =
                make_uint2(pkrtz2(v0, v1), pkrtz2(v2, v3));
          }
      }
      __syncthreads();
#pragma unroll
      for (int it = 0; it < 4; ++it) {
        int ch = tid + it * 256;
        int col = ch >> 4, sc = ch & 15;
        int gcol = n0 + half * 64 + col;
        int h = gcol / HD, d = gcol - h * HD;
        size_t dst = ((size_t)(b * NH + h) * HDP + d) * S_LEN + s0 + sc * 8;
        *(uint4*)&v_out[dst] = *(const uint4*)&T[col][sc * 8];
      }
    }
    return;
  }

  u16* out = mat == 0 ? q_out : k_out;
#pragma unroll
  for (int mi = 0; mi < 4; mi++)
#pragma unroll
    for (int ni = 0; ni < 4; ni++)
#pragma unroll
      for (int r = 0; r < 4; r++) {
        int row = m0 + wr * 64 + mi * 16 + quad * 4 + r;
        int col = n0 + wc * 64 + ni * 16 + lo;
        float v = (acc[mi][ni][r] + bias[col]) * scale;
        int b = row >> 11, s = row & 2047;
        int h = col / HD, d = col - h * HD;
        out[((size_t)((b * NH + h) * S_LEN + s)) * HDP + d] = f2b(v);
      }
}

// ---------------------------------------------------------------------------
// Wo GEMM: A = attn out HEAD-MAJOR [bh][s][48] bf16; out fp32 [8192][768].
// Tile 128x64, grid 768, double-buffered gld_lds staging (one barrier/K-step).
// LDS: 2 x (As 4096 + Bs 2048) = 12288 u16 = 24 KB. (round-12 verified)
// ---------------------------------------------------------------------------
__global__ __launch_bounds__(256) void gemm_wo(
    const u16* __restrict__ A, const u16* __restrict__ W,
    const float* __restrict__ bias, float* __restrict__ out)
{
  __shared__ __attribute__((aligned(16))) u16 smem[12288];

  const int tid = threadIdx.x;
  const int w = tid >> 6, lane = tid & 63, lo = lane & 15, quad = lane >> 4;
  const int bm = blockIdx.x & 63, bn = blockIdx.x >> 6;
  const int m0 = bm * 128, n0 = bn * 64;

  int ar[2], accg[2];
#pragma unroll
  for (int it = 0; it < 2; ++it) {
    int c = tid + it * 256, r = c >> 2, ccl = c & 3;
    ar[it] = m0 + r;
    accg[it] = (ccl ^ ((r >> 1) & 3)) * 8;
  }
  size_t boff;
  {
    int r = tid >> 2, ccl = tid & 3;
    boff = (size_t)(n0 + r) * DIM + (ccl ^ ((r >> 1) & 3)) * 8;
  }

  floatx4 acc[2][4];
#pragma unroll
  for (int mi = 0; mi < 2; mi++)
#pragma unroll
    for (int ni = 0; ni < 4; ni++) acc[mi][ni] = (floatx4){0.f, 0.f, 0.f, 0.f};

  // prologue: K-step 0 into buffer 0
#pragma unroll
  for (int it = 0; it < 2; ++it) {
    int row = ar[it], c8 = accg[it];
    int h = c8 / HD, d = c8 - h * HD;
    int b = row >> 11, s = row & 2047;
    gld_lds16(&A[((size_t)((b * NH + h) * S_LEN + s)) * HD + d],
              &smem[(it * 256 + w * 64) * 8]);
  }
  gld_lds16(&W[boff], &smem[4096 + (w * 64) * 8]);

  for (int ks = 0; ks < 24; ++ks) {
    const int cur = ks & 1;
    u16* Asc = smem + cur * 6144;
    u16* Bsc = Asc + 4096;
    __syncthreads();
    if (ks < 23) {
      const int kn = (ks + 1) * 32;
      u16* Asn = smem + (cur ^ 1) * 6144;
      u16* Bsn = Asn + 4096;
#pragma unroll
      for (int it = 0; it < 2; ++it) {
        int row = ar[it], c8 = kn + accg[it];
        int h = c8 / HD, d = c8 - h * HD;
        int b = row >> 11, s = row & 2047;
        gld_lds16(&A[((size_t)((b * NH + h) * S_LEN + s)) * HD + d],
                  &Asn[(it * 256 + w * 64) * 8]);
      }
      gld_lds16(&W[boff + kn], &Bsn[(w * 64) * 8]);
    }

    bf16x8 af[2], bfr[4];
#pragma unroll
    for (int mi = 0; mi < 2; mi++) {
      int row = w * 32 + mi * 16 + lo;
      int s = quad ^ ((row >> 1) & 3);
      af[mi] = *(const bf16x8*)&Asc[row * 32 + s * 8];
    }
#pragma unroll
    for (int ni = 0; ni < 4; ni++) {
      int row = ni * 16 + lo;
      int s = quad ^ ((row >> 1) & 3);
      bfr[ni] = *(const bf16x8*)&Bsc[row * 32 + s * 8];
    }
#pragma unroll
    for (int mi = 0; mi < 2; mi++)
#pragma unroll
      for (int ni = 0; ni < 4; ni++)
        acc[mi][ni] = __builtin_amdgcn_mfma_f32_16x16x32_bf16(af[mi], bfr[ni], acc[mi][ni], 0, 0, 0);
  }

#pragma unroll
  for (int mi = 0; mi < 2; mi++)
#pragma unroll
    for (int ni = 0; ni < 4; ni++)
#pragma unroll
      for (int r = 0; r < 4; r++) {
        int row = m0 + w * 32 + mi * 16 + quad * 4 + r;
        int col = n0 + ni * 16 + lo;
        out[(size_t)row * DIM + col] = acc[mi][ni][r] + bias[col];
      }
}

// ---------------------------------------------------------------------------
// Flash attention (round-9 structure): 32x32x16 MFMA, swapped QK^T, P in
// registers via cvt_pkrtz + permlane32_swap, f32 denominator, XCD swizzle,
// head-major O. ROUND 14: exp2-fold — Q arrives pre-scaled by lambda*log2e,
// so softmax uses v_exp_f32 directly (deletes 64 v_mul per wave-tile on the
// binding VALU pipe; VALUBusy 38% > MfmaUtil 23%).
// ---------------------------------------------------------------------------
#define STG_LOAD(k0n) do {                                                     \
  _Pragma("unroll")                                                            \
  for (int it = 0; it < 3; ++it) {                                             \
    int c = tid + it * 256;                                                    \
    if (c < 384) {                                                             \
      int r = c / 6, cc = c - r * 6;                                           \
      stg[it] = *(const uint4*)&K[base + (size_t)((k0n) + r) * HDP + cc * 8];  \
    } else {                                                                   \
      int c2 = c - 384, r = c2 >> 3, cc = c2 & 7;                              \
      stg[it] = *(const uint4*)&V[base + (size_t)r * S_LEN + (k0n) + cc * 8];  \
    }                                                                          \
  }                                                                            \
} while (0)

#define STG_WRITE(bufi) do {                                                   \
  _Pragma("unroll")                                                            \
  for (int it = 0; it < 3; ++it) {                                             \
    int c = tid + it * 256;                                                    \
    if (c < 384) {                                                             \
      int r = c / 6, cc = c - r * 6;                                           \
      *(uint4*)&Ks[bufi][r][cc * 8] = stg[it];                                 \
    } else {                                                                   \
      int c2 = c - 384, r = c2 >> 3, cc = c2 & 7;                              \
      *(uint4*)&Vt[bufi][r][cc * 8] = stg[it];                                 \
    }                                                                          \
  }                                                                            \
} while (0)

__global__ __launch_bounds__(256, 2) void attn_kernel(
    const u16* __restrict__ Q, const u16* __restrict__ K,
    const u16* __restrict__ V, u16* __restrict__ O)
{
  __shared__ __attribute__((aligned(16))) u16 Ks[2][64][56];  // keys x d(<48)
  __shared__ __attribute__((aligned(16))) u16 Vt[2][64][72];  // d x keys (f16)

  const int tid = threadIdx.x;
  const int w = tid >> 6, lane = tid & 63, l31 = lane & 31, hi = lane >> 5;
  const int flat = blockIdx.x;
  const int xcd = flat & 7, sub = flat >> 3;          // sub in [0,64)
  const int bh = xcd * 8 + (sub >> 3);                // 8 bh per XCD
  const int q0 = (sub & 7) * 256;                     // 8 q-blocks per bh
  const size_t base = (size_t)bh * S_LEN * HDP;

  bf16x8 qf[2][3];
#pragma unroll
  for (int t = 0; t < 2; t++)
#pragma unroll
    for (int ks = 0; ks < 3; ks++)
      qf[t][ks] = *(const bf16x8*)
          &Q[base + (size_t)(q0 + w * 64 + t * 32 + l31) * HDP + ks * 16 + hi * 8];

  floatx16 oacc[2][2];
#pragma unroll
  for (int t = 0; t < 2; t++)
#pragma unroll
    for (int nd = 0; nd < 2; nd++)
#pragma unroll
      for (int r = 0; r < 16; r++) oacc[t][nd][r] = 0.f;

  float l_lane[2] = {0.f, 0.f};

  uint4 stg[3];
  STG_LOAD(0);
  STG_WRITE(0);

  for (int ti = 0; ti < 32; ++ti) {
    const int cur = ti & 1;
    if (ti < 31) STG_LOAD((ti + 1) * 64);   // in flight across the barrier
    __syncthreads();

    bf16x8 ak[2][3];
#pragma unroll
    for (int na = 0; na < 2; na++)
#pragma unroll
      for (int ks = 0; ks < 3; ks++)
        ak[na][ks] = *(const bf16x8*)&Ks[cur][na * 32 + l31][ks * 16 + hi * 8];

    u32 pk[2][2][8];
#pragma unroll
    for (int t = 0; t < 2; t++) {
      floatx16 s0, s1;
#pragma unroll
      for (int r = 0; r < 16; r++) { s0[r] = 0.f; s1[r] = 0.f; }
#pragma unroll
      for (int ks = 0; ks < 3; ks++) {
        s0 = __builtin_amdgcn_mfma_f32_32x32x16_bf16(ak[0][ks], qf[t][ks], s0, 0, 0, 0);
        s1 = __builtin_amdgcn_mfma_f32_32x32x16_bf16(ak[1][ks], qf[t][ks], s1, 0, 0, 0);
      }
#pragma unroll
      for (int m = 0; m < 8; m++) {
        float a0 = __builtin_amdgcn_exp2f(s0[2 * m]);
        float a1 = __builtin_amdgcn_exp2f(s0[2 * m + 1]);
        float b0 = __builtin_amdgcn_exp2f(s1[2 * m]);
        float b1 = __builtin_amdgcn_exp2f(s1[2 * m + 1]);
        l_lane[t] += (a0 + a1) + (b0 + b1);
        pk[t][0][m] = pkrtz2(a0, a1);
        pk[t][1][m] = pkrtz2(b0, b1);
      }
    }

#pragma unroll
    for (int kt = 0; kt < 4; kt++) {
      f16x8 bv0 = *(const f16x8*)&Vt[cur][l31][kt * 16 + hi * 8];
      f16x8 bv1 = *(const f16x8*)&Vt[cur][32 + l31][kt * 16 + hi * 8];
      const int na = kt >> 1, k4 = (kt & 1) * 4;
#pragma unroll
      for (int t = 0; t < 2; t++) {
        u32 w0 = pk[t][na][k4 + 0], w2 = pk[t][na][k4 + 2];
        u32 w1 = pk[t][na][k4 + 1], w3 = pk[t][na][k4 + 3];
        pl32swap(w0, w2);
        pl32swap(w1, w3);
        union { u32 u[4]; f16x8 f; } af;
        af.u[0] = w0; af.u[1] = w1; af.u[2] = w2; af.u[3] = w3;
        oacc[t][0] = __builtin_amdgcn_mfma_f32_32x32x16_f16(af.f, bv0, oacc[t][0], 0, 0, 0);
        oacc[t][1] = __builtin_amdgcn_mfma_f32_32x32x16_f16(af.f, bv1, oacc[t][1], 0, 0, 0);
      }
    }

    if (ti < 31) STG_WRITE(cur ^ 1);
  }

  const size_t obase = (size_t)bh * S_LEN * HD;
  float lt_full[2];
#pragma unroll
  for (int t = 0; t < 2; t++)
    lt_full[t] = l_lane[t] + __shfl_xor(l_lane[t], 32);
#pragma unroll
  for (int t = 0; t < 2; t++) {
#pragma unroll
    for (int r = 0; r < 16; r++) {
      int q_local = (r & 3) + 8 * (r >> 2) + 4 * hi;
      float l_r = __shfl(lt_full[t], q_local);
      float inv = 1.f / l_r;
      int q = q0 + w * 64 + t * 32 + q_local;
      u16* orow = O + obase + (size_t)q * HD;
      orow[l31] = f2b(oacc[t][0][r] * inv);
      if (l31 < 16) orow[32 + l31] = f2b(oacc[t][1][r] * inv);
    }
  }
}

// ---------------------------------------------------------------------------
extern "C" void kernel_launch(void* const* d_in, const int* in_sizes, int n_in,
                              void* d_out, int out_size, void* d_ws, size_t ws_size,
                              hipStream_t stream)
{
  const float* x  = (const float*)d_in[0];
  const float* Wq = (const float*)d_in[1];
  const float* bq = (const float*)d_in[2];
  const float* Wk = (const float*)d_in[3];
  const float* bk = (const float*)d_in[4];
  const float* Wv = (const float*)d_in[5];
  const float* bv = (const float*)d_in[6];
  const float* Wo = (const float*)d_in[7];
  const float* bo = (const float*)d_in[8];

  u16* ws   = (u16*)d_ws;
  const size_t qkv_elems = (size_t)BHEADS * S_LEN * HDP;  // 8.39M u16 each
  u16* q_ws = ws;                                         // [bh][s][64] bf16
  u16* k_ws = q_ws + qkv_elems;                           // [bh][s][64] bf16
  u16* v_ws = k_ws + qkv_elems;                           // [bh][d][s]  f16 (V^T)
  u16* x_bf = v_ws + qkv_elems;                           // [8192][768] bf16
  u16* a_ws = x_bf;   // aliased: attn writes [bh][s][48] (6.29M u16 = x_bf size)
  u16* w_bf = x_bf + (size_t)8192 * DIM;                  // 4x[768][768] bf16
  u16* wo_bf = w_bf + (size_t)3 * W_ELEMS;

  cvt_all<<<dim3(4224), dim3(256), 0, stream>>>(x, Wq, Wk, Wv, Wo, x_bf, w_bf);
  gemm_qkv<<<dim3(1152), dim3(256), 0, stream>>>(x_bf, w_bf, bq, bk, bv,
                                                 q_ws, k_ws, v_ws);
  attn_kernel<<<dim3(512), dim3(256), 0, stream>>>(q_ws, k_ws, v_ws, a_ws);
  gemm_wo<<<dim3(768), dim3(256), 0, stream>>>(a_ws, wo_bf, bo, (float*)d_out);
}